// Round 8
// baseline (67.434 us; speedup 1.0000x reference)
//
#include <hip/hip_runtime.h>

#define H 512
#define W 512
#define BAND 32
#define NBANDS (H / BAND)   // 16
#define NT (W / 4)          // 128 tiles per row
#define NEG_INF (-3.402823466e38f)

__global__ void zero_acc_kernel(double* acc) {
    if (threadIdx.x == 0) acc[0] = 0.0;
}

// One block per (band of 32 output rows, image, tensor); 512 threads.
// Batches of 4 s-rows: thread = (row-slot q, 4-col tile t).
//  Stage A: load 3 raw rows (float4 + 2 scalars), build s[4] in regs,
//           per-tile prefix/suffix/max in regs, write S/P/M tile arrays. [bar]
//  Stage B: h(4t+k) = max(S_{t-2}[k], M_{t-1}, M_t, M_{t+1}, P_{t+2}[k])
//           (window 17 = partial tile + 3 full tiles + partial tile),
//           write h row. [bar]
//  Stage C: 1 col/thread, vertical 17-max via register van Herk (arr[16],
//           segments of 16), accumulate accMax. Virtual rows (outside [0,H))
//           contribute h = -inf and skip stages A/B (block-uniform).
// Avg-pool branch collapses to weighted sum of s (closed-form border counts).
__global__ __launch_bounds__(512, 8) void fused_kernel(const float* __restrict__ in0,
                                                       const float* __restrict__ in1,
                                                       double* __restrict__ acc) {
    const int band = blockIdx.x;
    const int img  = blockIdx.y;
    const float* __restrict__ im = (blockIdx.z ? in1 : in0) + (size_t)img * H * W;

    const int y0 = band * BAND, y1 = y0 + BAND;
    const int jlo_v = y0 - 8;            // first streamed s-row (may be virtual)

    __shared__ float Sarr[4][NT + 4][4]; // suffix per tile, idx = tile + 2
    __shared__ float Parr[4][NT + 4][4]; // prefix per tile
    __shared__ float Marr[4][NT + 4];    // tile max
    __shared__ float hrow[4][W];
    __shared__ double wsum[8];

    const int tid = threadIdx.x;
    const int q   = tid >> 7;            // row slot 0..3
    const int t   = tid & 127;           // tile 0..127
    const int c0  = t << 2;              // first col of tile
    const int x   = tid;                 // stage-C column

    // -inf pads: S read idx = t in [0,129] -> pads 0,1 ; P read idx = t+4 in
    // [4,131] -> pads 130,131 ; M read idx = t+1,t+3 in [1,130] -> pads 1,130.
    if (t < 2) {
        Sarr[q][t][0] = Sarr[q][t][1] = Sarr[q][t][2] = Sarr[q][t][3] = NEG_INF;
        Parr[q][130 + t][0] = Parr[q][130 + t][1] = NEG_INF;
        Parr[q][130 + t][2] = Parr[q][130 + t][3] = NEG_INF;
        Marr[q][t]       = NEG_INF;
        Marr[q][130 + t] = NEG_INF;
    }

    // per-col horizontal window sizes for avg branch (/289)
    float cxk[4];
#pragma unroll
    for (int k = 0; k < 4; ++k) {
        const int col = c0 + k;
        const int wlo = col - 8 > 0 ? col - 8 : 0;
        const int whi = col + 8 < W - 1 ? col + 8 : W - 1;
        cxk[k] = (float)(whi - wlo + 1) * (1.f / 289.f);
    }

    float accMax = 0.f, accSum = 0.f;
    float arr[16];                       // van Herk: prev-seg suffix / cur h
    float hc[4];

    for (int seg = 0; seg < 3; ++seg) {
        const bool emit = (seg != 0);
        float Pblk = NEG_INF;
#pragma unroll
        for (int r4 = 0; r4 < 4; ++r4) {
            const int j0 = jlo_v + seg * 16 + r4 * 4;   // block-uniform
            const bool real = (j0 >= 0) && (j0 < H);    // all 4 rows in/out together
            if (real) {
                // ---- stage A: s rows + per-tile prefix/suffix ----
                const int j = j0 + q;
                float us0 = 0.f, us1 = 0.f, us2 = 0.f, us3 = 0.f;
#pragma unroll
                for (int dr = -1; dr <= 1; ++dr) {
                    const int r = j + dr;
                    if (r >= 0 && r < H) {
                        const float* rp = im + (size_t)r * W + c0;
                        const float4 v = *(const float4*)rp;
                        const float lft = (c0 > 0)     ? rp[-1] : 0.f;
                        const float rgt = (c0 + 4 < W) ? rp[4]  : 0.f;
                        us0 += lft + v.x + v.y;
                        us1 += v.x + v.y + v.z;
                        us2 += v.y + v.z + v.w;
                        us3 += v.z + v.w + rgt;
                    }
                }
                const float s0 = us0 * (1.f / 9.f), s1 = us1 * (1.f / 9.f);
                const float s2 = us2 * (1.f / 9.f), s3 = us3 * (1.f / 9.f);
                {
                    const int rlo = j - 8 > y0 ? j - 8 : y0;
                    const int rhi = j + 8 < y1 - 1 ? j + 8 : y1 - 1;
                    accSum += (s0 * cxk[0] + s1 * cxk[1] + s2 * cxk[2] + s3 * cxk[3])
                              * (float)(rhi - rlo + 1);
                }
                const float p1v = fmaxf(s0, s1), p2v = fmaxf(p1v, s2), p3v = fmaxf(p2v, s3);
                const float q2v = fmaxf(s3, s2), q1v = fmaxf(q2v, s1), q0v = fmaxf(q1v, s0);
                *(float4*)&Sarr[q][t + 2][0] = make_float4(q0v, q1v, q2v, s3);
                *(float4*)&Parr[q][t + 2][0] = make_float4(s0, p1v, p2v, p3v);
                Marr[q][t + 2] = p3v;
                __syncthreads();                        // bar1: S/P/M ready

                // ---- stage B: combine tiles -> h ----
                const float4 Sv = *(const float4*)&Sarr[q][t][0];      // tile t-2
                const float4 Pv = *(const float4*)&Parr[q][t + 4][0];  // tile t+2
                const float mm = fmaxf(fmaxf(Marr[q][t + 1], p3v), Marr[q][t + 3]);
                const float h0 = fmaxf(fmaxf(Sv.x, mm), Pv.x);
                const float h1 = fmaxf(fmaxf(Sv.y, mm), Pv.y);
                const float h2 = fmaxf(fmaxf(Sv.z, mm), Pv.z);
                const float h3 = fmaxf(fmaxf(Sv.w, mm), Pv.w);
                *(float4*)&hrow[q][c0] = make_float4(h0, h1, h2, h3);
                __syncthreads();                        // bar2: hrow ready

                hc[0] = hrow[0][x]; hc[1] = hrow[1][x];
                hc[2] = hrow[2][x]; hc[3] = hrow[3][x];
            } else {
                hc[0] = hc[1] = hc[2] = hc[3] = NEG_INF; // virtual rows
            }
            // ---- stage C: vertical van Herk ingest + emit ----
#pragma unroll
            for (int qq = 0; qq < 4; ++qq) {
                const int p = r4 * 4 + qq;              // static index
                const float h = hc[qq];
                Pblk = fmaxf(Pblk, h);
                if (emit) accMax += fmaxf(arr[p], Pblk);
                arr[p] = h;
            }
        }
        // segment end: in-place suffix transform arr[p] = max(h[p..15])
#pragma unroll
        for (int r = 14; r >= 0; --r) arr[r] = fmaxf(arr[r], arr[r + 1]);
    }

    // ---- block reduction ----
    double v = (double)(accMax - accSum);
#pragma unroll
    for (int off = 32; off > 0; off >>= 1) v += __shfl_down(v, off, 64);
    const int lane = tid & 63, wave = tid >> 6;
    if (lane == 0) wsum[wave] = v;
    __syncthreads();
    if (tid == 0) {
        double b = 0.0;
#pragma unroll
        for (int wv = 0; wv < 8; ++wv) b += wsum[wv];
        atomicAdd(acc, b);
    }
}

__global__ void finalize_kernel(const double* __restrict__ acc, float* __restrict__ out) {
    if (threadIdx.x == 0) {
        // total pixels across both tensors = 2*32*512*512 = 16777216
        out[0] = (float)(1.0 - acc[0] * (1.0 / 16777216.0));
    }
}

extern "C" void kernel_launch(void* const* d_in, const int* in_sizes, int n_in,
                              void* d_out, int out_size, void* d_ws, size_t ws_size,
                              hipStream_t stream) {
    const float* in0 = (const float*)d_in[0];
    const float* in1 = (const float*)d_in[1];
    float* out = (float*)d_out;
    double* acc = (double*)d_ws;

    zero_acc_kernel<<<1, 64, 0, stream>>>(acc);
    fused_kernel<<<dim3(NBANDS, 32, 2), 512, 0, stream>>>(in0, in1, acc);
    finalize_kernel<<<1, 64, 0, stream>>>(acc, out);
}